// Round 11
// baseline (145.043 us; speedup 1.0000x reference)
//
#include <hip/hip_runtime.h>

// ActiveParticles forward pass, N=4096, float32.
// R22: FUSED single kernel (K1 + last-block collision tail) + tiny memset.
//   Ledger: R18 K2(no skip)=45.4; R19 K2(bitmap,2bar)=39.7 BEST; R21
//   K2(1bar,dbuf)=43.9 REGRESS (barriers exonerated; VALU bookkeeping cost).
//   R20: do-while runs I=9. Totals 115-124 vs kernel sum <80 => ~39us
//   harness fill + gaps in window; K1 never measured (<39us bound).
//   This round: (a) collision tail reverted to R19 EXACT structure (2
//   barriers/iter, single pos buffer, dbuf bitmap skip); (b) K2 dispatch
//   eliminated via last-block ticket: all 256 blocks run the N^2 pass,
//   producers release (syncthreads; tid0: threadfence + atomicAdd ticket),
//   256th block acquires (threadfence) and runs collisions with 512 thr
//   (8 slots/thread). Fused rocprof row = K1 + ~40 => K1 finally measured.
//   Ticket zeroed by 16B hipMemsetAsync (workspace is poison-filled between
//   reps; graph-capture-safe, R6-R12 pattern).
#define NPART 4096
#define PI_F 3.1415927410125732f
#define TWO_PI_F 6.2831854820251465f
#define SENT 4096              // sentinel neighbor id in padded quads

__device__ __forceinline__ float wrapf(float d) {
    // replicates: d = where(d <= -PI, mod(d, PI), d); d -= (d >= PI)*2PI
    if (d <= -PI_F) {
        d = fmodf(d, PI_F);
        if (d < 0.0f) d += PI_F;     // python-mod sign fixup
    }
    if (d >= PI_F) d -= TWO_PI_F;
    return d;
}

// ---------------- fused kernel: N^2 pass + last-block collision loop -------
__global__ __launch_bounds__(512)
void k_fused(const float* __restrict__ pr, const float* __restrict__ pim,
             const float* __restrict__ orr, const float* __restrict__ oim,
             const float* __restrict__ deltas,
             const float* __restrict__ rot_noise,
             const float* __restrict__ tn_re, const float* __restrict__ tn_im,
             float* __restrict__ out,
             uint2* __restrict__ recQuad, int* __restrict__ recC,
             unsigned short* __restrict__ recNbr16, int* __restrict__ gcnt) {
    constexpr float RR_F  = 8e-6f;
    constexpr float RR2   = RR_F * RR_F;
    constexpr float ROC_F = (float)(2.5e-5 + 3.15e-6);   // RO + RC (max radius)
    constexpr float ROC2  = ROC_F * ROC_F;
    constexpr float CUT_F = 14.3e-6f;                    // 2Rc + 8um candidate cutoff
    constexpr float CUT2  = CUT_F * CUT_F;

    // ---- K1 LDS ----
    __shared__ float2 lsP[512];                          // staged j positions
    __shared__ float2 lsO[512];                          // staged j orientations
    __shared__ float rA0[512], rA1[512], rA2[512], rA3[512], rA4[512];
    __shared__ float rB0[512], rB1[512], rB2[512], rB3[512], rB4[512];
    __shared__ float cr_[512], ci_[512];
    __shared__ int ncnt[16];
    __shared__ unsigned short nbrL[16 * 16];
    // ---- collision-tail LDS (only last block touches) ----
    __shared__ float2 pos[NPART + 2];                  // +sentinel, by orig id
    __shared__ __align__(16) unsigned short pool[128 * 16];  // c>4 tails
    __shared__ int flg[2];
    __shared__ int poolCnt;
    __shared__ unsigned bmp[2][132];                   // moved bitmaps
    __shared__ int lastFlag;

    int tid = threadIdx.x;
    int li = tid & 7, sl = tid >> 3;                     // sl in 0..63
    int i0 = blockIdx.x * 16 + li;                       // first owned i
    int i1 = i0 + 8;                                     // second owned i

    if (tid < 16) ncnt[tid] = 0;

    float pxA = pr[i0], pyA = pim[i0], oxA = orr[i0], oyA = oim[i0];
    float pxB = pr[i1], pyB = pim[i1], oxB = orr[i1], oyB = oim[i1];

    float nAr = 0.0f, SAre = 0.0f, SAim = 0.0f, oAre = 0.0f, oAim = 0.0f;
    float nBr = 0.0f, SBre = 0.0f, SBim = 0.0f, oBre = 0.0f, oBim = 0.0f;
    float cs_re = 0.0f, cs_im = 0.0f;

    for (int c = 0; c < 8; ++c) {
        int j0 = c * 512;
        __syncthreads();
        float jr = pr[j0 + tid], ji = pim[j0 + tid];
        lsP[tid] = make_float2(jr, ji);
        lsO[tid] = make_float2(orr[j0 + tid], oim[j0 + tid]);
        cs_re += jr; cs_im += ji;                        // each j staged exactly once
        __syncthreads();
#pragma unroll
        for (int t = 0; t < 8; ++t) {
            int jj = sl * 8 + ((t + sl) & 7);            // bank-swizzled: conflict-free
            int j = j0 + jj;
            float2 pv = lsP[jj];
            float drA = pxA - pv.x, diA = pyA - pv.y;
            float d2A = drA * drA + diA * diA;
            float drB = pxB - pv.x, diB = pyB - pv.y;
            float d2B = drB * drB + diB * diB;
            // ROC is the largest radius: exact superset test for both i's.
            if (__any((d2A <= ROC2) | (d2B <= ROC2))) {  // rare slow path
                float2 ov = lsO[jj];
                // ---- i0 ----
                if (d2A <= ROC2) { oAre += ov.x; oAim += ov.y; }
                float dotA = oxA * ov.x + oyA * ov.y;    // in-front: cos(ai-aj)>0
                if ((d2A <= RR2) & (dotA > 0.0f) & (j != i0)) {
                    nAr += 1.0f; SAre += pv.x; SAim += pv.y;
                }
                if (d2A <= CUT2 && j != i0) {
                    int slot = atomicAdd(&ncnt[li], 1);
                    if (slot < 16) nbrL[li * 16 + slot] = (unsigned short)j;
                }
                // ---- i1 ----
                if (d2B <= ROC2) { oBre += ov.x; oBim += ov.y; }
                float dotB = oxB * ov.x + oyB * ov.y;
                if ((d2B <= RR2) & (dotB > 0.0f) & (j != i1)) {
                    nBr += 1.0f; SBre += pv.x; SBim += pv.y;
                }
                if (d2B <= CUT2 && j != i1) {
                    int slot = atomicAdd(&ncnt[li + 8], 1);
                    if (slot < 16) nbrL[(li + 8) * 16 + slot] = (unsigned short)j;
                }
            }
        }
    }

    rA0[tid] = nAr; rA1[tid] = SAre; rA2[tid] = SAim; rA3[tid] = oAre; rA4[tid] = oAim;
    rB0[tid] = nBr; rB1[tid] = SBre; rB2[tid] = SBim; rB3[tid] = oBre; rB4[tid] = oBim;
    cr_[tid] = cs_re; ci_[tid] = cs_im;
    __syncthreads();
    for (int s = 256; s >= 8; s >>= 1) {                 // tree (li groups, stride>=8)
        if (tid < s) {
            rA0[tid] += rA0[tid + s]; rA1[tid] += rA1[tid + s];
            rA2[tid] += rA2[tid + s]; rA3[tid] += rA3[tid + s];
            rA4[tid] += rA4[tid + s];
            rB0[tid] += rB0[tid + s]; rB1[tid] += rB1[tid + s];
            rB2[tid] += rB2[tid + s]; rB3[tid] += rB3[tid + s];
            rB4[tid] += rB4[tid + s];
            cr_[tid] += cr_[tid + s];  ci_[tid] += ci_[tid + s];
        }
        __syncthreads();
    }
    if (tid < 4) { cr_[tid] += cr_[tid + 4]; ci_[tid] += ci_[tid + 4]; }
    __syncthreads();
    if (tid < 2) { cr_[tid] += cr_[tid + 2]; ci_[tid] += ci_[tid + 2]; }
    __syncthreads();
    if (tid == 0) { cr_[0] += cr_[1]; ci_[0] += ci_[1]; }
    __syncthreads();

    if (tid < 16) {   // per-particle epilogue; i = blk*16 + tid
        int i = blockIdx.x * 16 + tid;
        float n_r, S_re, S_im, o_re, o_im, px, py, ox, oy;
        if (tid < 8) {
            n_r = rA0[tid]; S_re = rA1[tid]; S_im = rA2[tid];
            o_re = rA3[tid]; o_im = rA4[tid];
            px = pxA; py = pyA; ox = oxA; oy = oyA;      // this thread's li == tid
        } else {
            int g = tid - 8;
            n_r = rB0[g]; S_re = rB1[g]; S_im = rB2[g];
            o_re = rB3[g]; o_im = rB4[g];
            px = pxB; py = pyB; ox = oxB; oy = oyB;      // li == tid-8 -> i1 == i
        }

        float maxnr = fmaxf(n_r, 1.0f);
        float sgn = (n_r > 0.0f) ? 1.0f : 0.0f;
        float Sre = S_re / maxnr - px * sgn;
        float Sim = S_im / maxnr - py * sgn;
        float d_re = -Sre, d_im = -Sim;

        float cmsx = cr_[0] * (1.0f / 4096.0f);
        float cmsy = ci_[0] * (1.0f / 4096.0f);
        float Ps_re = cmsx - px;                         // n_a = 4096 > 0
        float Ps_im = cmsy - py;

        float dl = deltas[i];
        float cd = cosf(dl), sd = sinf(dl);
        float l_re = Ps_re * cd - Ps_im * sd;            // Ps * e^{+i d}
        float l_im = Ps_re * sd + Ps_im * cd;
        float r_re = Ps_re * cd + Ps_im * sd;            // Ps * e^{-i d}
        float r_im = Ps_im * cd - Ps_re * sd;

        float nb   = fmaxf(hypotf(o_re, o_im), 1e-14f);
        float na_l = fmaxf(hypotf(l_re, l_im), 1e-14f);
        float na_r = fmaxf(hypotf(r_re, r_im), 1e-14f);
        float csl = (l_re * o_re + l_im * o_im) / (na_l * nb);
        float csr = (r_re * o_re + r_im * o_im) / (na_r * nb);
        float b_re = (csl >= csr) ? l_re : r_re;
        float b_im = (csl >= csr) ? l_im : r_im;

        float ai = atan2f(oy, ox);
        bool has_rep = (d_re != 0.0f) || (d_im != 0.0f);
        float att;
        if (has_rep) att = wrapf(atan2f(d_im, d_re) - ai);
        else         att = wrapf(atan2f(b_im, b_re) - ai);

        constexpr float GDD  = (float)(0.2 * 25.0 * 0.0028);  // DT*GAMMA*DR
        constexpr float S2DR = 0.07483314773547883f;           // sqrt(2*DR)
        constexpr float SDT  = 0.44721359549995793f;           // sqrt(DT)
        float theta = GDD * sinf(att) + (rot_noise[i] * S2DR) * SDT;
        float rr_ = cosf(theta), ri_ = sinf(theta);

        float no_re = ox * rr_ - oy * ri_;
        float no_im = ox * ri_ + oy * rr_;

        constexpr float DTVEL = (float)(0.2 * 5e-7);
        constexpr float C1 = 0.70710678118654752f;             // sqrt(0.5)
        constexpr float C2 = 1.6733200530681511e-07f;          // sqrt(2*DT_TRANS)
        float t_re = DTVEL * ox + ((tn_re[i] * C1) * C2) * SDT;
        float t_im = DTVEL * oy + ((tn_im[i] * C1) * C2) * SDT;
        float p0x = px + t_re, p0y = py + t_im;

        float2* o2 = (float2*)out;
        o2[i]            = make_float2(p0x, p0y);        // tail reads + may overwrite
        o2[1 * 4096 + i] = make_float2(no_re, no_im);
        o2[2 * 4096 + i] = make_float2(o_re, o_im);
        o2[3 * 4096 + i] = make_float2(l_re, l_im);
        o2[4 * 4096 + i] = make_float2(r_re, r_im);

        // dense record build: unconditional, no atomics, no gcnt.
        int c = min(ncnt[tid], 16);
        unsigned q0 = (c > 0) ? nbrL[tid * 16 + 0] : (unsigned)SENT;
        unsigned q1 = (c > 1) ? nbrL[tid * 16 + 1] : (unsigned)SENT;
        unsigned q2 = (c > 2) ? nbrL[tid * 16 + 2] : (unsigned)SENT;
        unsigned q3 = (c > 3) ? nbrL[tid * 16 + 3] : (unsigned)SENT;
        recQuad[i] = make_uint2(q0 | (q1 << 16), q2 | (q3 << 16));
        recC[i] = c;
        if (c > 4) {                                     // rare tail (~2%)
            int cp = (c + 3) & ~3;
            for (int m = 4; m < cp; ++m)
                recNbr16[i * 16 + m] = (m < c) ? nbrL[tid * 16 + m]
                                               : (unsigned short)SENT;
        }
    }

    // ---------------- last-block ticket (release/acquire) ------------------
    __syncthreads();                        // all this block's stores issued
    if (tid == 0) {
        __threadfence();                    // device-scope release (L2 wb)
        unsigned t = atomicAdd((unsigned*)gcnt, 1u);
        lastFlag = (t == 255u);
    }
    __syncthreads();
    if (!lastFlag) return;                  // 255 blocks exit; 1 continues
    __threadfence();                        // acquire: invalidate stale caches

    // ---------------- collision tail: R19 structure, 512 thr, 8 slots ------
    constexpr float TWO_RC  = (float)(2.0 * 3.15e-6);
    constexpr float TWO_RC2 = TWO_RC * TWO_RC;
    constexpr float C21RC   = (float)(2.1 * 3.15e-6);

    if (tid == 0) {
        pos[SENT] = make_float2(1e9f, 1e9f);           // sentinel: never collides
        flg[0] = 0; flg[1] = 0; poolCnt = 0;
    }
    if (tid < 132) { bmp[0][tid] = 0u; bmp[1][tid] = 0u; }

    const float2* o2in = (const float2*)out;           // p0 (fence-visible)
    float myx[8], myy[8];
    int myc[8], myo[8];
    int nq0[8], nq1[8], nq2[8], nq3[8];
    bool pm[8];                                        // self-moved-last-iter
#pragma unroll
    for (int s = 0; s < 8; ++s) {                      // dense, coalesced init
        int i = s * 512 + tid;
        float2 p = o2in[i];
        myx[s] = p.x; myy[s] = p.y;
        pos[i] = p;
        uint2 q = recQuad[i];
        nq0[s] = q.x & 0xffff; nq1[s] = q.x >> 16;
        nq2[s] = q.y & 0xffff; nq3[s] = q.y >> 16;
        myc[s] = recC[i];
        myo[s] = -1;
        pm[s] = true;                                  // it==0 is all-dirty anyway
    }
    __syncthreads();                                   // pos[] + poolCnt ready

#pragma unroll
    for (int s = 0; s < 8; ++s) {                      // stage rare tails to LDS
        if (myc[s] > 4) {
            int r = atomicAdd(&poolCnt, 1);
            if (r < 128) {
                int i = s * 512 + tid;
                const uint4* src = (const uint4*)&recNbr16[i * 16];
                uint4* dst = (uint4*)&pool[r * 16];
                dst[0] = src[0]; dst[1] = src[1];
                myo[s] = r;
            }                                          // overflow: global fallback
        }
    }
    __syncthreads();                                   // pool ready

    for (int it = 0; it < 30; ++it) {
        int cur = it & 1, nxt = cur ^ 1;
        if (tid < 132) bmp[nxt][tid] = 0u;             // clear next bitmap

        float nx[8], ny[8];
        int ncs[8];
#pragma unroll
        for (int s = 0; s < 8; ++s) {                    // read phase
            ncs[s] = 0;
            int c = myc[s];
            if (c > 0) {
                bool dirty;
                if (it == 0 || c > 4) {
                    dirty = true;
                } else {
                    unsigned hit = pm[s] ? 1u : 0u;
                    hit |= (bmp[cur][nq0[s] >> 5] >> (nq0[s] & 31)) & 1u;
                    hit |= (bmp[cur][nq1[s] >> 5] >> (nq1[s] & 31)) & 1u;
                    hit |= (bmp[cur][nq2[s] >> 5] >> (nq2[s] & 31)) & 1u;
                    hit |= (bmp[cur][nq3[s] >> 5] >> (nq3[s] & 31)) & 1u;
                    dirty = hit != 0u;
                }
                if (dirty) {
                    float px = myx[s], py = myy[s];
                    float mre = 0.0f, mim = 0.0f;
                    int nc = 0;
                    float2 q0 = pos[nq0[s]], q1 = pos[nq1[s]];
                    float2 q2 = pos[nq2[s]], q3 = pos[nq3[s]];
#define COLL_ONE(q)                                                     \
                    {                                                   \
                        float dr = (q).x - px, di = (q).y - py;         \
                        float d2 = dr * dr + di * di;                   \
                        if (d2 <= TWO_RC2) {                            \
                            float a = sqrtf(d2);                        \
                            float mm = (C21RC - a) * 0.5f / a;          \
                            mre += dr * mm; mim += di * mm; ++nc;       \
                        }                                               \
                    }
                    COLL_ONE(q0) COLL_ONE(q1) COLL_ONE(q2) COLL_ONE(q3)
                    for (int m0 = 4; m0 < c; m0 += 4) {  // rare: c>4 tail
                        uint2 w;
                        if (myo[s] >= 0)
                            w = *(const uint2*)&pool[myo[s] * 16 + m0];
                        else
                            w = *(const uint2*)&recNbr16[(s * 512 + tid) * 16 + m0];
                        int j0 = w.x & 0xffff, j1 = w.x >> 16;
                        int j2 = w.y & 0xffff, j3 = w.y >> 16;
                        float2 t0 = pos[j0], t1 = pos[j1], t2 = pos[j2], t3 = pos[j3];
                        COLL_ONE(t0) COLL_ONE(t1) COLL_ONE(t2) COLL_ONE(t3)
                    }
#undef COLL_ONE
                    ncs[s] = nc;
                    nx[s] = px - mre; ny[s] = py - mim;
                }
            }
        }
        __syncthreads();                                 // all pos reads done
        int any = 0;
#pragma unroll
        for (int s = 0; s < 8; ++s) {                    // write phase (movers only)
            pm[s] = (ncs[s] > 0);
            if (ncs[s] > 0) {                            // non-mover: identity, skip
                int i = s * 512 + tid;
                myx[s] = nx[s]; myy[s] = ny[s];
                pos[i] = make_float2(nx[s], ny[s]);
                atomicOr(&bmp[nxt][i >> 5], 1u << (i & 31));
            }
            any |= ncs[s];
        }
        if (any) flg[it & 1] = 1;                        // benign race: all write 1
        if (tid == 0) flg[(it + 1) & 1] = 0;             // reset next-iter flag
        __syncthreads();                                 // writes + flag visible
        if (flg[it & 1] == 0) break;                     // do-while converged
    }

    float2* o2 = (float2*)out;                           // final positions, all i
#pragma unroll
    for (int s = 0; s < 8; ++s)
        o2[s * 512 + tid] = make_float2(myx[s], myy[s]);
}

extern "C" void kernel_launch(void* const* d_in, const int* in_sizes, int n_in,
                              void* d_out, int out_size, void* d_ws, size_t ws_size,
                              hipStream_t stream) {
    const float* pos_re = (const float*)d_in[0];
    const float* pos_im = (const float*)d_in[1];
    const float* ori_re = (const float*)d_in[2];
    const float* ori_im = (const float*)d_in[3];
    const float* deltas = (const float*)d_in[4];
    const float* rot_noise = (const float*)d_in[5];
    const float* tn_re = (const float*)d_in[6];
    const float* tn_im = (const float*)d_in[7];
    float* out = (float*)d_out;

    // workspace: ticket + dense records
    int* gcnt = (int*)d_ws;                                 // ticket (16 B)
    uint2* recQuad = (uint2*)((char*)d_ws + 16);            // 4096 (32 KB)
    int* recC = (int*)(recQuad + NPART);                    // 4096 (16 KB)
    unsigned short* recNbr16 = (unsigned short*)(recC + NPART);  // 4096*16 (128 KB)

    hipMemsetAsync(gcnt, 0, 16, stream);                    // ticket reset (poisoned ws)
    k_fused<<<256, 512, 0, stream>>>(pos_re, pos_im, ori_re, ori_im,
                                     deltas, rot_noise, tn_re, tn_im,
                                     out, recQuad, recC, recNbr16, gcnt);
}

// Round 12
// 117.854 us; speedup vs baseline: 1.2307x; 1.2307x over previous
//
#include <hip/hip_runtime.h>

// ActiveParticles forward pass, N=4096, float32.
// R23: revert R22 fusion (84.4us fused, total 145 — tail at 8 waves lost
//   R11's 16-wave gain; fusion only saved the launch gap). Back to the best
//   measured two-dispatch structure: K2 = R19 verbatim (39.7us, bitmap skip,
//   1024 thr, 2 barriers/iter). R22's one payoff: K1 bracketed at ~35-44us
//   (fused 84.4 minus tail 40-50), VALUBusy 3.8% chip-wide => K1 is
//   stall-bound: 16 staging barriers (8 chunks x 2) with only 4 loads of
//   latency-hiding between them.
// R23 K1 change: SINGLE-SHOT STAGING. Stage all 4096 pos+ori into LDS once
//   (64 KB; block total ~89 KB < 160 KB; grid=256=#CUs so 1 block/CU
//   suffices). Staging barriers 16 -> 1; the 32 staging loads issue
//   back-to-back (full MLP); the 64 j-tests/thread run uninterrupted.
//   Bit-exact: same per-thread j order (jj = c*512 + sl*8 + ((t+sl)&7)),
//   same banking (chunk offset is bank-aligned), same accumulation order,
//   reduction + epilogue untouched.
#define NPART 4096
#define PI_F 3.1415927410125732f
#define TWO_PI_F 6.2831854820251465f
#define SENT 4096              // sentinel neighbor id in padded quads

__device__ __forceinline__ float wrapf(float d) {
    // replicates: d = where(d <= -PI, mod(d, PI), d); d -= (d >= PI)*2PI
    if (d <= -PI_F) {
        d = fmodf(d, PI_F);
        if (d < 0.0f) d += PI_F;     // python-mod sign fixup
    }
    if (d >= PI_F) d -= TWO_PI_F;
    return d;
}

// ---------------- K1: interaction pass + dense record build ----------------
__global__ __launch_bounds__(512)
void k_interact(const float* __restrict__ pr, const float* __restrict__ pim,
                const float* __restrict__ orr, const float* __restrict__ oim,
                const float* __restrict__ deltas,
                const float* __restrict__ rot_noise,
                const float* __restrict__ tn_re, const float* __restrict__ tn_im,
                float* __restrict__ out,
                uint2* __restrict__ recQuad, int* __restrict__ recC,
                unsigned short* __restrict__ recNbr16) {
    constexpr float RR_F  = 8e-6f;
    constexpr float RR2   = RR_F * RR_F;
    constexpr float ROC_F = (float)(2.5e-5 + 3.15e-6);   // RO + RC (max radius)
    constexpr float ROC2  = ROC_F * ROC_F;
    constexpr float CUT_F = 14.3e-6f;                    // 2Rc + 8um candidate cutoff
    constexpr float CUT2  = CUT_F * CUT_F;

    __shared__ float2 lsP[NPART];                        // ALL j positions (32 KB)
    __shared__ float2 lsO[NPART];                        // ALL j orientations (32 KB)
    __shared__ float rA0[512], rA1[512], rA2[512], rA3[512], rA4[512];
    __shared__ float rB0[512], rB1[512], rB2[512], rB3[512], rB4[512];
    __shared__ float cr_[512], ci_[512];
    __shared__ int ncnt[16];
    __shared__ unsigned short nbrL[16 * 16];

    int tid = threadIdx.x;
    int li = tid & 7, sl = tid >> 3;                     // sl in 0..63
    int i0 = blockIdx.x * 16 + li;                       // first owned i
    int i1 = i0 + 8;                                     // second owned i

    if (tid < 16) ncnt[tid] = 0;

    float pxA = pr[i0], pyA = pim[i0], oxA = orr[i0], oyA = oim[i0];
    float pxB = pr[i1], pyB = pim[i1], oxB = orr[i1], oyB = oim[i1];

    float nAr = 0.0f, SAre = 0.0f, SAim = 0.0f, oAre = 0.0f, oAim = 0.0f;
    float nBr = 0.0f, SBre = 0.0f, SBim = 0.0f, oBre = 0.0f, oBim = 0.0f;
    float cs_re = 0.0f, cs_im = 0.0f;

    // single-shot staging: 32 back-to-back loads, ONE barrier
#pragma unroll
    for (int k = 0; k < 8; ++k) {
        int j = k * 512 + tid;
        float jr = pr[j], ji = pim[j];
        lsP[j] = make_float2(jr, ji);
        lsO[j] = make_float2(orr[j], oim[j]);
        cs_re += jr; cs_im += ji;                        // each j staged exactly once
    }
    __syncthreads();

    for (int c = 0; c < 8; ++c) {
#pragma unroll
        for (int t = 0; t < 8; ++t) {
            int jj = c * 512 + sl * 8 + ((t + sl) & 7);  // bank-swizzled: conflict-free
            int j = jj;                                  // LDS index == global id
            float2 pv = lsP[jj];
            float drA = pxA - pv.x, diA = pyA - pv.y;
            float d2A = drA * drA + diA * diA;
            float drB = pxB - pv.x, diB = pyB - pv.y;
            float d2B = drB * drB + diB * diB;
            // ROC is the largest radius: exact superset test for both i's.
            if (__any((d2A <= ROC2) | (d2B <= ROC2))) {  // rare slow path
                float2 ov = lsO[jj];
                // ---- i0 ----
                if (d2A <= ROC2) { oAre += ov.x; oAim += ov.y; }
                float dotA = oxA * ov.x + oyA * ov.y;    // in-front: cos(ai-aj)>0
                if ((d2A <= RR2) & (dotA > 0.0f) & (j != i0)) {
                    nAr += 1.0f; SAre += pv.x; SAim += pv.y;
                }
                if (d2A <= CUT2 && j != i0) {
                    int slot = atomicAdd(&ncnt[li], 1);
                    if (slot < 16) nbrL[li * 16 + slot] = (unsigned short)j;
                }
                // ---- i1 ----
                if (d2B <= ROC2) { oBre += ov.x; oBim += ov.y; }
                float dotB = oxB * ov.x + oyB * ov.y;
                if ((d2B <= RR2) & (dotB > 0.0f) & (j != i1)) {
                    nBr += 1.0f; SBre += pv.x; SBim += pv.y;
                }
                if (d2B <= CUT2 && j != i1) {
                    int slot = atomicAdd(&ncnt[li + 8], 1);
                    if (slot < 16) nbrL[(li + 8) * 16 + slot] = (unsigned short)j;
                }
            }
        }
    }

    rA0[tid] = nAr; rA1[tid] = SAre; rA2[tid] = SAim; rA3[tid] = oAre; rA4[tid] = oAim;
    rB0[tid] = nBr; rB1[tid] = SBre; rB2[tid] = SBim; rB3[tid] = oBre; rB4[tid] = oBim;
    cr_[tid] = cs_re; ci_[tid] = cs_im;
    __syncthreads();
    for (int s = 256; s >= 8; s >>= 1) {                 // tree (li groups, stride>=8)
        if (tid < s) {
            rA0[tid] += rA0[tid + s]; rA1[tid] += rA1[tid + s];
            rA2[tid] += rA2[tid + s]; rA3[tid] += rA3[tid + s];
            rA4[tid] += rA4[tid + s];
            rB0[tid] += rB0[tid + s]; rB1[tid] += rB1[tid + s];
            rB2[tid] += rB2[tid + s]; rB3[tid] += rB3[tid + s];
            rB4[tid] += rB4[tid + s];
            cr_[tid] += cr_[tid + s];  ci_[tid] += ci_[tid + s];
        }
        __syncthreads();
    }
    if (tid < 4) { cr_[tid] += cr_[tid + 4]; ci_[tid] += ci_[tid + 4]; }
    __syncthreads();
    if (tid < 2) { cr_[tid] += cr_[tid + 2]; ci_[tid] += ci_[tid + 2]; }
    __syncthreads();
    if (tid == 0) { cr_[0] += cr_[1]; ci_[0] += ci_[1]; }
    __syncthreads();

    if (tid < 16) {   // per-particle epilogue; i = blk*16 + tid
        int i = blockIdx.x * 16 + tid;
        float n_r, S_re, S_im, o_re, o_im, px, py, ox, oy;
        if (tid < 8) {
            n_r = rA0[tid]; S_re = rA1[tid]; S_im = rA2[tid];
            o_re = rA3[tid]; o_im = rA4[tid];
            px = pxA; py = pyA; ox = oxA; oy = oyA;      // this thread's li == tid
        } else {
            int g = tid - 8;
            n_r = rB0[g]; S_re = rB1[g]; S_im = rB2[g];
            o_re = rB3[g]; o_im = rB4[g];
            px = pxB; py = pyB; ox = oxB; oy = oyB;      // li == tid-8 -> i1 == i
        }

        float maxnr = fmaxf(n_r, 1.0f);
        float sgn = (n_r > 0.0f) ? 1.0f : 0.0f;
        float Sre = S_re / maxnr - px * sgn;
        float Sim = S_im / maxnr - py * sgn;
        float d_re = -Sre, d_im = -Sim;

        float cmsx = cr_[0] * (1.0f / 4096.0f);
        float cmsy = ci_[0] * (1.0f / 4096.0f);
        float Ps_re = cmsx - px;                         // n_a = 4096 > 0
        float Ps_im = cmsy - py;

        float dl = deltas[i];
        float cd = cosf(dl), sd = sinf(dl);
        float l_re = Ps_re * cd - Ps_im * sd;            // Ps * e^{+i d}
        float l_im = Ps_re * sd + Ps_im * cd;
        float r_re = Ps_re * cd + Ps_im * sd;            // Ps * e^{-i d}
        float r_im = Ps_im * cd - Ps_re * sd;

        float nb   = fmaxf(hypotf(o_re, o_im), 1e-14f);
        float na_l = fmaxf(hypotf(l_re, l_im), 1e-14f);
        float na_r = fmaxf(hypotf(r_re, r_im), 1e-14f);
        float csl = (l_re * o_re + l_im * o_im) / (na_l * nb);
        float csr = (r_re * o_re + r_im * o_im) / (na_r * nb);
        float b_re = (csl >= csr) ? l_re : r_re;
        float b_im = (csl >= csr) ? l_im : r_im;

        float ai = atan2f(oy, ox);
        bool has_rep = (d_re != 0.0f) || (d_im != 0.0f);
        float att;
        if (has_rep) att = wrapf(atan2f(d_im, d_re) - ai);
        else         att = wrapf(atan2f(b_im, b_re) - ai);

        constexpr float GDD  = (float)(0.2 * 25.0 * 0.0028);  // DT*GAMMA*DR
        constexpr float S2DR = 0.07483314773547883f;           // sqrt(2*DR)
        constexpr float SDT  = 0.44721359549995793f;           // sqrt(DT)
        float theta = GDD * sinf(att) + (rot_noise[i] * S2DR) * SDT;
        float rr_ = cosf(theta), ri_ = sinf(theta);

        float no_re = ox * rr_ - oy * ri_;
        float no_im = ox * ri_ + oy * rr_;

        constexpr float DTVEL = (float)(0.2 * 5e-7);
        constexpr float C1 = 0.70710678118654752f;             // sqrt(0.5)
        constexpr float C2 = 1.6733200530681511e-07f;          // sqrt(2*DT_TRANS)
        float t_re = DTVEL * ox + ((tn_re[i] * C1) * C2) * SDT;
        float t_im = DTVEL * oy + ((tn_im[i] * C1) * C2) * SDT;
        float p0x = px + t_re, p0y = py + t_im;

        float2* o2 = (float2*)out;
        o2[i]            = make_float2(p0x, p0y);        // K2 reads + may overwrite
        o2[1 * 4096 + i] = make_float2(no_re, no_im);
        o2[2 * 4096 + i] = make_float2(o_re, o_im);
        o2[3 * 4096 + i] = make_float2(l_re, l_im);
        o2[4 * 4096 + i] = make_float2(r_re, r_im);

        // dense record build: unconditional, no atomics, no gcnt.
        int c = min(ncnt[tid], 16);
        unsigned q0 = (c > 0) ? nbrL[tid * 16 + 0] : (unsigned)SENT;
        unsigned q1 = (c > 1) ? nbrL[tid * 16 + 1] : (unsigned)SENT;
        unsigned q2 = (c > 2) ? nbrL[tid * 16 + 2] : (unsigned)SENT;
        unsigned q3 = (c > 3) ? nbrL[tid * 16 + 3] : (unsigned)SENT;
        recQuad[i] = make_uint2(q0 | (q1 << 16), q2 | (q3 << 16));
        recC[i] = c;
        if (c > 4) {                                     // rare tail (~2%)
            int cp = (c + 3) & ~3;
            for (int m = 4; m < cp; ++m)
                recNbr16[i * 16 + m] = (m < c) ? nbrL[tid * 16 + m]
                                               : (unsigned short)SENT;
        }
    }
}

// ---------------- K2: collision loop, ONE workgroup (1024 thr), dense ------
__global__ __launch_bounds__(1024)
void k_coll_all(const uint2* __restrict__ recQuad, const int* __restrict__ recC,
                const unsigned short* __restrict__ recNbr16,
                float* __restrict__ out) {
    constexpr float TWO_RC  = (float)(2.0 * 3.15e-6);
    constexpr float TWO_RC2 = TWO_RC * TWO_RC;
    constexpr float C21RC   = (float)(2.1 * 3.15e-6);

    __shared__ float2 pos[NPART + 2];                  // +sentinel, by orig id
    __shared__ __align__(16) unsigned short pool[128 * 16];  // c>4 tails
    __shared__ int flg[2];
    __shared__ int poolCnt;
    __shared__ unsigned bmp[2][132];                   // moved bitmaps
                                                       // (4096 bits + sentinel word)

    int tid = threadIdx.x;
    if (tid == 0) {
        pos[SENT] = make_float2(1e9f, 1e9f);           // sentinel: never collides
        flg[0] = 0; flg[1] = 0; poolCnt = 0;
    }
    if (tid < 132) { bmp[0][tid] = 0u; bmp[1][tid] = 0u; }

    const float2* o2in = (const float2*)out;           // p0 written by K1
    float myx[4], myy[4];
    int myc[4], myo[4];
    int nq0[4], nq1[4], nq2[4], nq3[4];
    bool pm[4];                                        // self-moved-last-iter
#pragma unroll
    for (int s = 0; s < 4; ++s) {                      // dense, coalesced init
        int i = s * 1024 + tid;
        float2 p = o2in[i];
        myx[s] = p.x; myy[s] = p.y;
        pos[i] = p;
        uint2 q = recQuad[i];
        nq0[s] = q.x & 0xffff; nq1[s] = q.x >> 16;
        nq2[s] = q.y & 0xffff; nq3[s] = q.y >> 16;
        myc[s] = recC[i];
        myo[s] = -1;
        pm[s] = true;                                  // it==0 is all-dirty anyway
    }
    __syncthreads();                                   // pos[] + poolCnt ready

#pragma unroll
    for (int s = 0; s < 4; ++s) {                      // stage rare tails to LDS
        if (myc[s] > 4) {
            int r = atomicAdd(&poolCnt, 1);
            if (r < 128) {
                int i = s * 1024 + tid;
                const uint4* src = (const uint4*)&recNbr16[i * 16];
                uint4* dst = (uint4*)&pool[r * 16];
                dst[0] = src[0]; dst[1] = src[1];
                myo[s] = r;
            }                                          // overflow: global fallback
        }
    }
    __syncthreads();                                   // pool ready

    for (int it = 0; it < 30; ++it) {
        int cur = it & 1, nxt = cur ^ 1;
        // clear NEXT bitmap (last read at it-1's read phase; filled in this
        // iter's write phase; mid-barrier orders clear-before-set)
        if (tid < 132) bmp[nxt][tid] = 0u;

        float nx[4], ny[4];
        int ncs[4];
#pragma unroll
        for (int s = 0; s < 4; ++s) {                    // read phase
            ncs[s] = 0;
            int c = myc[s];
            if (c > 0) {
                // dirty check: recompute only if self or a candidate neighbor
                // moved last iteration (exact — see header comment).
                bool dirty;
                if (it == 0 || c > 4) {
                    dirty = true;
                } else {
                    unsigned hit = pm[s] ? 1u : 0u;
                    hit |= (bmp[cur][nq0[s] >> 5] >> (nq0[s] & 31)) & 1u;
                    hit |= (bmp[cur][nq1[s] >> 5] >> (nq1[s] & 31)) & 1u;
                    hit |= (bmp[cur][nq2[s] >> 5] >> (nq2[s] & 31)) & 1u;
                    hit |= (bmp[cur][nq3[s] >> 5] >> (nq3[s] & 31)) & 1u;
                    dirty = hit != 0u;
                }
                if (dirty) {
                    float px = myx[s], py = myy[s];
                    float mre = 0.0f, mim = 0.0f;
                    int nc = 0;
                    float2 q0 = pos[nq0[s]], q1 = pos[nq1[s]];
                    float2 q2 = pos[nq2[s]], q3 = pos[nq3[s]];
#define COLL_ONE(q)                                                     \
                    {                                                   \
                        float dr = (q).x - px, di = (q).y - py;         \
                        float d2 = dr * dr + di * di;                   \
                        if (d2 <= TWO_RC2) {                            \
                            float a = sqrtf(d2);                        \
                            float mm = (C21RC - a) * 0.5f / a;          \
                            mre += dr * mm; mim += di * mm; ++nc;       \
                        }                                               \
                    }
                    COLL_ONE(q0) COLL_ONE(q1) COLL_ONE(q2) COLL_ONE(q3)
                    for (int m0 = 4; m0 < c; m0 += 4) {  // rare: c>4 tail
                        uint2 w;
                        if (myo[s] >= 0)
                            w = *(const uint2*)&pool[myo[s] * 16 + m0];
                        else
                            w = *(const uint2*)&recNbr16[(s * 1024 + tid) * 16 + m0];
                        int j0 = w.x & 0xffff, j1 = w.x >> 16;
                        int j2 = w.y & 0xffff, j3 = w.y >> 16;
                        float2 t0 = pos[j0], t1 = pos[j1], t2 = pos[j2], t3 = pos[j3];
                        COLL_ONE(t0) COLL_ONE(t1) COLL_ONE(t2) COLL_ONE(t3)
                    }
#undef COLL_ONE
                    ncs[s] = nc;
                    nx[s] = px - mre; ny[s] = py - mim;
                }
            }
        }
        __syncthreads();                                 // all pos reads done
#pragma unroll
        for (int s = 0; s < 4; ++s) {                    // write phase (movers only)
            pm[s] = (ncs[s] > 0);
            if (ncs[s] > 0) {                            // non-mover: identity, skip
                int i = s * 1024 + tid;
                myx[s] = nx[s]; myy[s] = ny[s];
                pos[i] = make_float2(nx[s], ny[s]);
                atomicOr(&bmp[nxt][i >> 5], 1u << (i & 31));
            }
        }
        int any = ncs[0] | ncs[1] | ncs[2] | ncs[3];
        if (any) flg[it & 1] = 1;                        // benign race: all write 1
        if (tid == 0) flg[(it + 1) & 1] = 0;             // reset next-iter flag
        __syncthreads();                                 // writes + flag visible
        if (flg[it & 1] == 0) break;                     // do-while converged
    }

    float2* o2 = (float2*)out;                           // final positions, all i
#pragma unroll
    for (int s = 0; s < 4; ++s)
        o2[s * 1024 + tid] = make_float2(myx[s], myy[s]);
}

extern "C" void kernel_launch(void* const* d_in, const int* in_sizes, int n_in,
                              void* d_out, int out_size, void* d_ws, size_t ws_size,
                              hipStream_t stream) {
    const float* pos_re = (const float*)d_in[0];
    const float* pos_im = (const float*)d_in[1];
    const float* ori_re = (const float*)d_in[2];
    const float* ori_im = (const float*)d_in[3];
    const float* deltas = (const float*)d_in[4];
    const float* rot_noise = (const float*)d_in[5];
    const float* tn_re = (const float*)d_in[6];
    const float* tn_im = (const float*)d_in[7];
    float* out = (float*)d_out;

    // dense workspace layout (no counters, no memset dispatch)
    uint2* recQuad = (uint2*)d_ws;                          // 4096 (32 KB)
    int* recC = (int*)(recQuad + NPART);                    // 4096 (16 KB)
    unsigned short* recNbr16 = (unsigned short*)(recC + NPART);  // 4096*16 (128 KB)

    k_interact<<<256, 512, 0, stream>>>(pos_re, pos_im, ori_re, ori_im,
                                        deltas, rot_noise, tn_re, tn_im,
                                        out, recQuad, recC, recNbr16);
    k_coll_all<<<1, 1024, 0, stream>>>(recQuad, recC, recNbr16, out);
}

// Round 13
// 117.581 us; speedup vs baseline: 1.2336x; 1.0023x over previous
//
#include <hip/hip_runtime.h>

// ActiveParticles forward pass, N=4096, float32.
// Ledger (per-dispatch rocprof): fill 39.7us (harness poison, timed window,
//   immovable); K2 = 39.6us (R19 structure: bitmap skip, 1024 thr, 2 bar/iter;
//   9 iterations measured via R20 canary; insensitive to barrier halving
//   (R21 +4), full-gather (R18 +5.7), fusion (R22 +25) => near structural
//   floor ~35). K1 < 39.5 (never in top-5), single-shot staged since R23.
// R24 (this round): K1 shuffle reduction — 10-barrier LDS tree -> 2 barriers.
//   Reduction groups are stride-8 (same li): within a 64-lane wave that is a
//   3-step __shfl_xor butterfly (masks 8/16/32). Lanes 0-7/wave write 12
//   per-(wave,li) partials to part[12][64] (3KB, replaces 24KB tree arrays);
//   barrier; tid<8 folds 8 wave-partials per li (ascending order, det.);
//   barrier; epilogue reads red[][], sums 8 cs partials locally.
//   NOTE: summation order changes => absmax may shift from 4.768e-7 (same
//   magnitude expected; short well-conditioned sums). K2 byte-identical
//   (control rows in top-5).
#define NPART 4096
#define PI_F 3.1415927410125732f
#define TWO_PI_F 6.2831854820251465f
#define SENT 4096              // sentinel neighbor id in padded quads

__device__ __forceinline__ float wrapf(float d) {
    // replicates: d = where(d <= -PI, mod(d, PI), d); d -= (d >= PI)*2PI
    if (d <= -PI_F) {
        d = fmodf(d, PI_F);
        if (d < 0.0f) d += PI_F;     // python-mod sign fixup
    }
    if (d >= PI_F) d -= TWO_PI_F;
    return d;
}

// ---------------- K1: interaction pass + dense record build ----------------
__global__ __launch_bounds__(512)
void k_interact(const float* __restrict__ pr, const float* __restrict__ pim,
                const float* __restrict__ orr, const float* __restrict__ oim,
                const float* __restrict__ deltas,
                const float* __restrict__ rot_noise,
                const float* __restrict__ tn_re, const float* __restrict__ tn_im,
                float* __restrict__ out,
                uint2* __restrict__ recQuad, int* __restrict__ recC,
                unsigned short* __restrict__ recNbr16) {
    constexpr float RR_F  = 8e-6f;
    constexpr float RR2   = RR_F * RR_F;
    constexpr float ROC_F = (float)(2.5e-5 + 3.15e-6);   // RO + RC (max radius)
    constexpr float ROC2  = ROC_F * ROC_F;
    constexpr float CUT_F = 14.3e-6f;                    // 2Rc + 8um candidate cutoff
    constexpr float CUT2  = CUT_F * CUT_F;

    __shared__ float2 lsP[NPART];                        // ALL j positions (32 KB)
    __shared__ float2 lsO[NPART];                        // ALL j orientations (32 KB)
    __shared__ float part[12][64];                       // per-(wave,li) partials
    __shared__ float red[12][8];                         // final per-li sums
    __shared__ int ncnt[16];
    __shared__ unsigned short nbrL[16 * 16];

    int tid = threadIdx.x;
    int li = tid & 7, sl = tid >> 3;                     // sl in 0..63
    int i0 = blockIdx.x * 16 + li;                       // first owned i
    int i1 = i0 + 8;                                     // second owned i

    if (tid < 16) ncnt[tid] = 0;

    float pxA = pr[i0], pyA = pim[i0], oxA = orr[i0], oyA = oim[i0];
    float pxB = pr[i1], pyB = pim[i1], oxB = orr[i1], oyB = oim[i1];

    float nAr = 0.0f, SAre = 0.0f, SAim = 0.0f, oAre = 0.0f, oAim = 0.0f;
    float nBr = 0.0f, SBre = 0.0f, SBim = 0.0f, oBre = 0.0f, oBim = 0.0f;
    float cs_re = 0.0f, cs_im = 0.0f;

    // single-shot staging: 32 back-to-back loads, ONE barrier (R23)
#pragma unroll
    for (int k = 0; k < 8; ++k) {
        int j = k * 512 + tid;
        float jr = pr[j], ji = pim[j];
        lsP[j] = make_float2(jr, ji);
        lsO[j] = make_float2(orr[j], oim[j]);
        cs_re += jr; cs_im += ji;                        // each j staged exactly once
    }
    __syncthreads();

    for (int c = 0; c < 8; ++c) {
#pragma unroll
        for (int t = 0; t < 8; ++t) {
            int jj = c * 512 + sl * 8 + ((t + sl) & 7);  // bank-swizzled: conflict-free
            int j = jj;                                  // LDS index == global id
            float2 pv = lsP[jj];
            float drA = pxA - pv.x, diA = pyA - pv.y;
            float d2A = drA * drA + diA * diA;
            float drB = pxB - pv.x, diB = pyB - pv.y;
            float d2B = drB * drB + diB * diB;
            // ROC is the largest radius: exact superset test for both i's.
            if (__any((d2A <= ROC2) | (d2B <= ROC2))) {  // rare slow path
                float2 ov = lsO[jj];
                // ---- i0 ----
                if (d2A <= ROC2) { oAre += ov.x; oAim += ov.y; }
                float dotA = oxA * ov.x + oyA * ov.y;    // in-front: cos(ai-aj)>0
                if ((d2A <= RR2) & (dotA > 0.0f) & (j != i0)) {
                    nAr += 1.0f; SAre += pv.x; SAim += pv.y;
                }
                if (d2A <= CUT2 && j != i0) {
                    int slot = atomicAdd(&ncnt[li], 1);
                    if (slot < 16) nbrL[li * 16 + slot] = (unsigned short)j;
                }
                // ---- i1 ----
                if (d2B <= ROC2) { oBre += ov.x; oBim += ov.y; }
                float dotB = oxB * ov.x + oyB * ov.y;
                if ((d2B <= RR2) & (dotB > 0.0f) & (j != i1)) {
                    nBr += 1.0f; SBre += pv.x; SBim += pv.y;
                }
                if (d2B <= CUT2 && j != i1) {
                    int slot = atomicAdd(&ncnt[li + 8], 1);
                    if (slot < 16) nbrL[(li + 8) * 16 + slot] = (unsigned short)j;
                }
            }
        }
    }

    // R24 shuffle reduction: stride-8 groups == 3-step xor butterfly in-wave.
    {
        float v0 = nAr, v1 = SAre, v2 = SAim, v3 = oAre, v4 = oAim;
        float v5 = nBr, v6 = SBre, v7 = SBim, v8 = oBre, v9 = oBim;
        float v10 = cs_re, v11 = cs_im;
#define RED3(v) { v += __shfl_xor(v, 8); v += __shfl_xor(v, 16); v += __shfl_xor(v, 32); }
        RED3(v0) RED3(v1) RED3(v2) RED3(v3) RED3(v4) RED3(v5)
        RED3(v6) RED3(v7) RED3(v8) RED3(v9) RED3(v10) RED3(v11)
#undef RED3
        int lane = tid & 63, wv = tid >> 6;
        if (lane < 8) {                                  // lane == li here
            int col = wv * 8 + lane;
            part[0][col] = v0;  part[1][col] = v1;  part[2][col] = v2;
            part[3][col] = v3;  part[4][col] = v4;  part[5][col] = v5;
            part[6][col] = v6;  part[7][col] = v7;  part[8][col] = v8;
            part[9][col] = v9;  part[10][col] = v10; part[11][col] = v11;
        }
    }
    __syncthreads();
    if (tid < 8) {                                       // fold 8 wave-partials/li
#pragma unroll
        for (int av = 0; av < 12; ++av) {
            float s = 0.0f;
#pragma unroll
            for (int w = 0; w < 8; ++w) s += part[av][w * 8 + tid];
            red[av][tid] = s;
        }
    }
    __syncthreads();

    if (tid < 16) {   // per-particle epilogue; i = blk*16 + tid
        int i = blockIdx.x * 16 + tid;
        float n_r, S_re, S_im, o_re, o_im, px, py, ox, oy;
        if (tid < 8) {
            n_r = red[0][tid]; S_re = red[1][tid]; S_im = red[2][tid];
            o_re = red[3][tid]; o_im = red[4][tid];
            px = pxA; py = pyA; ox = oxA; oy = oyA;      // this thread's li == tid
        } else {
            int g = tid - 8;
            n_r = red[5][g]; S_re = red[6][g]; S_im = red[7][g];
            o_re = red[8][g]; o_im = red[9][g];
            px = pxB; py = pyB; ox = oxB; oy = oyB;      // li == tid-8 -> i1 == i
        }

        float csr_ = 0.0f, csi_ = 0.0f;                  // cs totals (det. order)
#pragma unroll
        for (int k = 0; k < 8; ++k) { csr_ += red[10][k]; csi_ += red[11][k]; }

        float maxnr = fmaxf(n_r, 1.0f);
        float sgn = (n_r > 0.0f) ? 1.0f : 0.0f;
        float Sre = S_re / maxnr - px * sgn;
        float Sim = S_im / maxnr - py * sgn;
        float d_re = -Sre, d_im = -Sim;

        float cmsx = csr_ * (1.0f / 4096.0f);
        float cmsy = csi_ * (1.0f / 4096.0f);
        float Ps_re = cmsx - px;                         // n_a = 4096 > 0
        float Ps_im = cmsy - py;

        float dl = deltas[i];
        float cd = cosf(dl), sd = sinf(dl);
        float l_re = Ps_re * cd - Ps_im * sd;            // Ps * e^{+i d}
        float l_im = Ps_re * sd + Ps_im * cd;
        float r_re = Ps_re * cd + Ps_im * sd;            // Ps * e^{-i d}
        float r_im = Ps_im * cd - Ps_re * sd;

        float nb   = fmaxf(hypotf(o_re, o_im), 1e-14f);
        float na_l = fmaxf(hypotf(l_re, l_im), 1e-14f);
        float na_r = fmaxf(hypotf(r_re, r_im), 1e-14f);
        float csl = (l_re * o_re + l_im * o_im) / (na_l * nb);
        float csr2 = (r_re * o_re + r_im * o_im) / (na_r * nb);
        float b_re = (csl >= csr2) ? l_re : r_re;
        float b_im = (csl >= csr2) ? l_im : r_im;

        float ai = atan2f(oy, ox);
        bool has_rep = (d_re != 0.0f) || (d_im != 0.0f);
        float att;
        if (has_rep) att = wrapf(atan2f(d_im, d_re) - ai);
        else         att = wrapf(atan2f(b_im, b_re) - ai);

        constexpr float GDD  = (float)(0.2 * 25.0 * 0.0028);  // DT*GAMMA*DR
        constexpr float S2DR = 0.07483314773547883f;           // sqrt(2*DR)
        constexpr float SDT  = 0.44721359549995793f;           // sqrt(DT)
        float theta = GDD * sinf(att) + (rot_noise[i] * S2DR) * SDT;
        float rr_ = cosf(theta), ri_ = sinf(theta);

        float no_re = ox * rr_ - oy * ri_;
        float no_im = ox * ri_ + oy * rr_;

        constexpr float DTVEL = (float)(0.2 * 5e-7);
        constexpr float C1 = 0.70710678118654752f;             // sqrt(0.5)
        constexpr float C2 = 1.6733200530681511e-07f;          // sqrt(2*DT_TRANS)
        float t_re = DTVEL * ox + ((tn_re[i] * C1) * C2) * SDT;
        float t_im = DTVEL * oy + ((tn_im[i] * C1) * C2) * SDT;
        float p0x = px + t_re, p0y = py + t_im;

        float2* o2 = (float2*)out;
        o2[i]            = make_float2(p0x, p0y);        // K2 reads + may overwrite
        o2[1 * 4096 + i] = make_float2(no_re, no_im);
        o2[2 * 4096 + i] = make_float2(o_re, o_im);
        o2[3 * 4096 + i] = make_float2(l_re, l_im);
        o2[4 * 4096 + i] = make_float2(r_re, r_im);

        // dense record build: unconditional, no atomics, no gcnt.
        int c = min(ncnt[tid], 16);
        unsigned q0 = (c > 0) ? nbrL[tid * 16 + 0] : (unsigned)SENT;
        unsigned q1 = (c > 1) ? nbrL[tid * 16 + 1] : (unsigned)SENT;
        unsigned q2 = (c > 2) ? nbrL[tid * 16 + 2] : (unsigned)SENT;
        unsigned q3 = (c > 3) ? nbrL[tid * 16 + 3] : (unsigned)SENT;
        recQuad[i] = make_uint2(q0 | (q1 << 16), q2 | (q3 << 16));
        recC[i] = c;
        if (c > 4) {                                     // rare tail (~2%)
            int cp = (c + 3) & ~3;
            for (int m = 4; m < cp; ++m)
                recNbr16[i * 16 + m] = (m < c) ? nbrL[tid * 16 + m]
                                               : (unsigned short)SENT;
        }
    }
}

// ---------------- K2: collision loop, ONE workgroup (1024 thr), dense ------
__global__ __launch_bounds__(1024)
void k_coll_all(const uint2* __restrict__ recQuad, const int* __restrict__ recC,
                const unsigned short* __restrict__ recNbr16,
                float* __restrict__ out) {
    constexpr float TWO_RC  = (float)(2.0 * 3.15e-6);
    constexpr float TWO_RC2 = TWO_RC * TWO_RC;
    constexpr float C21RC   = (float)(2.1 * 3.15e-6);

    __shared__ float2 pos[NPART + 2];                  // +sentinel, by orig id
    __shared__ __align__(16) unsigned short pool[128 * 16];  // c>4 tails
    __shared__ int flg[2];
    __shared__ int poolCnt;
    __shared__ unsigned bmp[2][132];                   // moved bitmaps
                                                       // (4096 bits + sentinel word)

    int tid = threadIdx.x;
    if (tid == 0) {
        pos[SENT] = make_float2(1e9f, 1e9f);           // sentinel: never collides
        flg[0] = 0; flg[1] = 0; poolCnt = 0;
    }
    if (tid < 132) { bmp[0][tid] = 0u; bmp[1][tid] = 0u; }

    const float2* o2in = (const float2*)out;           // p0 written by K1
    float myx[4], myy[4];
    int myc[4], myo[4];
    int nq0[4], nq1[4], nq2[4], nq3[4];
    bool pm[4];                                        // self-moved-last-iter
#pragma unroll
    for (int s = 0; s < 4; ++s) {                      // dense, coalesced init
        int i = s * 1024 + tid;
        float2 p = o2in[i];
        myx[s] = p.x; myy[s] = p.y;
        pos[i] = p;
        uint2 q = recQuad[i];
        nq0[s] = q.x & 0xffff; nq1[s] = q.x >> 16;
        nq2[s] = q.y & 0xffff; nq3[s] = q.y >> 16;
        myc[s] = recC[i];
        myo[s] = -1;
        pm[s] = true;                                  // it==0 is all-dirty anyway
    }
    __syncthreads();                                   // pos[] + poolCnt ready

#pragma unroll
    for (int s = 0; s < 4; ++s) {                      // stage rare tails to LDS
        if (myc[s] > 4) {
            int r = atomicAdd(&poolCnt, 1);
            if (r < 128) {
                int i = s * 1024 + tid;
                const uint4* src = (const uint4*)&recNbr16[i * 16];
                uint4* dst = (uint4*)&pool[r * 16];
                dst[0] = src[0]; dst[1] = src[1];
                myo[s] = r;
            }                                          // overflow: global fallback
        }
    }
    __syncthreads();                                   // pool ready

    for (int it = 0; it < 30; ++it) {
        int cur = it & 1, nxt = cur ^ 1;
        // clear NEXT bitmap (last read at it-1's read phase; filled in this
        // iter's write phase; mid-barrier orders clear-before-set)
        if (tid < 132) bmp[nxt][tid] = 0u;

        float nx[4], ny[4];
        int ncs[4];
#pragma unroll
        for (int s = 0; s < 4; ++s) {                    // read phase
            ncs[s] = 0;
            int c = myc[s];
            if (c > 0) {
                // dirty check: recompute only if self or a candidate neighbor
                // moved last iteration (exact — see header comment).
                bool dirty;
                if (it == 0 || c > 4) {
                    dirty = true;
                } else {
                    unsigned hit = pm[s] ? 1u : 0u;
                    hit |= (bmp[cur][nq0[s] >> 5] >> (nq0[s] & 31)) & 1u;
                    hit |= (bmp[cur][nq1[s] >> 5] >> (nq1[s] & 31)) & 1u;
                    hit |= (bmp[cur][nq2[s] >> 5] >> (nq2[s] & 31)) & 1u;
                    hit |= (bmp[cur][nq3[s] >> 5] >> (nq3[s] & 31)) & 1u;
                    dirty = hit != 0u;
                }
                if (dirty) {
                    float px = myx[s], py = myy[s];
                    float mre = 0.0f, mim = 0.0f;
                    int nc = 0;
                    float2 q0 = pos[nq0[s]], q1 = pos[nq1[s]];
                    float2 q2 = pos[nq2[s]], q3 = pos[nq3[s]];
#define COLL_ONE(q)                                                     \
                    {                                                   \
                        float dr = (q).x - px, di = (q).y - py;         \
                        float d2 = dr * dr + di * di;                   \
                        if (d2 <= TWO_RC2) {                            \
                            float a = sqrtf(d2);                        \
                            float mm = (C21RC - a) * 0.5f / a;          \
                            mre += dr * mm; mim += di * mm; ++nc;       \
                        }                                               \
                    }
                    COLL_ONE(q0) COLL_ONE(q1) COLL_ONE(q2) COLL_ONE(q3)
                    for (int m0 = 4; m0 < c; m0 += 4) {  // rare: c>4 tail
                        uint2 w;
                        if (myo[s] >= 0)
                            w = *(const uint2*)&pool[myo[s] * 16 + m0];
                        else
                            w = *(const uint2*)&recNbr16[(s * 1024 + tid) * 16 + m0];
                        int j0 = w.x & 0xffff, j1 = w.x >> 16;
                        int j2 = w.y & 0xffff, j3 = w.y >> 16;
                        float2 t0 = pos[j0], t1 = pos[j1], t2 = pos[j2], t3 = pos[j3];
                        COLL_ONE(t0) COLL_ONE(t1) COLL_ONE(t2) COLL_ONE(t3)
                    }
#undef COLL_ONE
                    ncs[s] = nc;
                    nx[s] = px - mre; ny[s] = py - mim;
                }
            }
        }
        __syncthreads();                                 // all pos reads done
#pragma unroll
        for (int s = 0; s < 4; ++s) {                    // write phase (movers only)
            pm[s] = (ncs[s] > 0);
            if (ncs[s] > 0) {                            // non-mover: identity, skip
                int i = s * 1024 + tid;
                myx[s] = nx[s]; myy[s] = ny[s];
                pos[i] = make_float2(nx[s], ny[s]);
                atomicOr(&bmp[nxt][i >> 5], 1u << (i & 31));
            }
        }
        int any = ncs[0] | ncs[1] | ncs[2] | ncs[3];
        if (any) flg[it & 1] = 1;                        // benign race: all write 1
        if (tid == 0) flg[(it + 1) & 1] = 0;             // reset next-iter flag
        __syncthreads();                                 // writes + flag visible
        if (flg[it & 1] == 0) break;                     // do-while converged
    }

    float2* o2 = (float2*)out;                           // final positions, all i
#pragma unroll
    for (int s = 0; s < 4; ++s)
        o2[s * 1024 + tid] = make_float2(myx[s], myy[s]);
}

extern "C" void kernel_launch(void* const* d_in, const int* in_sizes, int n_in,
                              void* d_out, int out_size, void* d_ws, size_t ws_size,
                              hipStream_t stream) {
    const float* pos_re = (const float*)d_in[0];
    const float* pos_im = (const float*)d_in[1];
    const float* ori_re = (const float*)d_in[2];
    const float* ori_im = (const float*)d_in[3];
    const float* deltas = (const float*)d_in[4];
    const float* rot_noise = (const float*)d_in[5];
    const float* tn_re = (const float*)d_in[6];
    const float* tn_im = (const float*)d_in[7];
    float* out = (float*)d_out;

    // dense workspace layout (no counters, no memset dispatch)
    uint2* recQuad = (uint2*)d_ws;                          // 4096 (32 KB)
    int* recC = (int*)(recQuad + NPART);                    // 4096 (16 KB)
    unsigned short* recNbr16 = (unsigned short*)(recC + NPART);  // 4096*16 (128 KB)

    k_interact<<<256, 512, 0, stream>>>(pos_re, pos_im, ori_re, ori_im,
                                        deltas, rot_noise, tn_re, tn_im,
                                        out, recQuad, recC, recNbr16);
    k_coll_all<<<1, 1024, 0, stream>>>(recQuad, recC, recNbr16, out);
}